// Round 1
// baseline (94.779 us; speedup 1.0000x reference)
//
#include <hip/hip_runtime.h>

#ifndef __has_builtin
#define __has_builtin(x) 0
#endif

__device__ __forceinline__ float fexp2(float x) {
#if __has_builtin(__builtin_amdgcn_exp2f)
  return __builtin_amdgcn_exp2f(x);   // v_exp_f32 (native exp2)
#else
  return exp2f(x);
#endif
}
__device__ __forceinline__ float frcp(float x) {
#if __has_builtin(__builtin_amdgcn_rcpf)
  return __builtin_amdgcn_rcpf(x);    // v_rcp_f32
#else
  return 1.0f / x;
#endif
}

#define L_DIM 128
#define D_DIM 128
#define NBH   32
static constexpr float TWO_LOG2E = 2.88539008177792681f;  // 2*log2(e)

// ---------------- Phase 1: P = (A @ W^T + b) * scale ----------------
// grid 256 = mat(2) x bh(32) x lc(4); 256 threads (16x16).
// Out tile: 32 rows (lc*32..) x all 128 cols. Per-thread 2l x 8e.
__global__ __launch_bounds__(256)
void proj_kernel(const float* __restrict__ X, const float* __restrict__ Y,
                 const float* __restrict__ W1, const float* __restrict__ b1,
                 const float* __restrict__ W2, const float* __restrict__ b2,
                 float* __restrict__ Xs, float* __restrict__ Yp) {
  const int bid = blockIdx.x;
  const int mat = bid & 1;
  const int bh  = (bid >> 1) & 31;
  const int lc  = bid >> 6;  // 0..3

  const float* __restrict__ A  = mat ? Y  : X;
  const float* __restrict__ W  = mat ? W2 : W1;
  const float* __restrict__ bb = mat ? b2 : b1;
  float* __restrict__ P = mat ? Yp : Xs;
  const float scale = mat ? 1.0f : TWO_LOG2E;

  __shared__ __align__(16) float Xc[32][36];    // [l][d-chunk], pad 36
  __shared__ __align__(16) float WT[32][132];   // W^T chunk [d][e], pad 132

  const int tid = threadIdx.x;
  const int tx = tid & 15, ty = tid >> 4;

  float acc[2][8];
#pragma unroll
  for (int i = 0; i < 2; ++i)
#pragma unroll
    for (int j = 0; j < 8; ++j) acc[i][j] = 0.f;

  const float* Arow = A + (size_t)(bh * L_DIM + lc * 32) * D_DIM;

  for (int dc = 0; dc < 4; ++dc) {
    __syncthreads();
    {  // stage X chunk: 32 l x 32 d, one float4/thread, coalesced
      const int l = tid >> 3, dq = tid & 7;
      const float4 v = *(const float4*)(Arow + l * D_DIM + dc * 32 + dq * 4);
      *(float4*)&Xc[l][dq * 4] = v;
    }
    {  // stage W^T chunk: 128 e x 32 d; thread -> (e = tid/2, 16 d's)
      const int e = tid >> 1, half = tid & 1;
      const float* wrow = W + e * D_DIM + dc * 32 + half * 16;
      const float4 v0 = *(const float4*)(wrow + 0);
      const float4 v1 = *(const float4*)(wrow + 4);
      const float4 v2 = *(const float4*)(wrow + 8);
      const float4 v3 = *(const float4*)(wrow + 12);
      const int d0 = half * 16;
      WT[d0 +  0][e] = v0.x; WT[d0 +  1][e] = v0.y; WT[d0 +  2][e] = v0.z; WT[d0 +  3][e] = v0.w;
      WT[d0 +  4][e] = v1.x; WT[d0 +  5][e] = v1.y; WT[d0 +  6][e] = v1.z; WT[d0 +  7][e] = v1.w;
      WT[d0 +  8][e] = v2.x; WT[d0 +  9][e] = v2.y; WT[d0 + 10][e] = v2.z; WT[d0 + 11][e] = v2.w;
      WT[d0 + 12][e] = v3.x; WT[d0 + 13][e] = v3.y; WT[d0 + 14][e] = v3.z; WT[d0 + 15][e] = v3.w;
    }
    __syncthreads();
#pragma unroll
    for (int dd = 0; dd < 32; ++dd) {
      const float x0 = Xc[ty][dd];        // broadcast reads, conflict-free
      const float x1 = Xc[ty + 16][dd];
      const float4 w0 = *(const float4*)&WT[dd][4 * tx];        // 2-way max
      const float4 w1 = *(const float4*)&WT[dd][64 + 4 * tx];
      acc[0][0] += x0 * w0.x; acc[0][1] += x0 * w0.y; acc[0][2] += x0 * w0.z; acc[0][3] += x0 * w0.w;
      acc[0][4] += x0 * w1.x; acc[0][5] += x0 * w1.y; acc[0][6] += x0 * w1.z; acc[0][7] += x0 * w1.w;
      acc[1][0] += x1 * w0.x; acc[1][1] += x1 * w0.y; acc[1][2] += x1 * w0.z; acc[1][3] += x1 * w0.w;
      acc[1][4] += x1 * w1.x; acc[1][5] += x1 * w1.y; acc[1][6] += x1 * w1.z; acc[1][7] += x1 * w1.w;
    }
  }

  const float4 bv0 = *(const float4*)(bb + 4 * tx);
  const float4 bv1 = *(const float4*)(bb + 64 + 4 * tx);
#pragma unroll
  for (int i = 0; i < 2; ++i) {
    float* prow = P + (size_t)(bh * L_DIM + lc * 32 + ty + 16 * i) * D_DIM;
    float4 o0, o1;
    o0.x = (acc[i][0] + bv0.x) * scale; o0.y = (acc[i][1] + bv0.y) * scale;
    o0.z = (acc[i][2] + bv0.z) * scale; o0.w = (acc[i][3] + bv0.w) * scale;
    o1.x = (acc[i][4] + bv1.x) * scale; o1.y = (acc[i][5] + bv1.y) * scale;
    o1.z = (acc[i][6] + bv1.z) * scale; o1.w = (acc[i][7] + bv1.w) * scale;
    *(float4*)(prow + 4 * tx) = o0;
    *(float4*)(prow + 64 + 4 * tx) = o1;
  }
}

// ---------------- Phase 2: out = C0 - 2 * sum_d w3[d] / (1 + exp2(Xs*Yp)) --
// grid 512 = bh(32) x lt(4) x mt(4); 256 threads; 32x32 tile, 2x2/thread.
#define ACC4(WC, XA, XB, YA, YB)                  \
  a00 += (WC) * frcp(1.f + fexp2((XA) * (YA)));   \
  a01 += (WC) * frcp(1.f + fexp2((XA) * (YB)));   \
  a10 += (WC) * frcp(1.f + fexp2((XB) * (YA)));   \
  a11 += (WC) * frcp(1.f + fexp2((XB) * (YB)));

__global__ __launch_bounds__(256)
void tanh_outer_kernel(const float* __restrict__ Xs, const float* __restrict__ Yp,
                       const float* __restrict__ w3, const float* __restrict__ b3,
                       float* __restrict__ out) {
  const int bid = blockIdx.x;
  const int bh = bid >> 4;
  const int lt = (bid >> 2) & 3;
  const int mt = bid & 3;

  __shared__ __align__(16) float Xt[32][132];
  __shared__ __align__(16) float Yt[32][132];
  __shared__ __align__(16) float w3s[128];

  const int tid = threadIdx.x;
  const int tx = tid & 15, ty = tid >> 4;

  const float* Xrow = Xs + (size_t)(bh * L_DIM + lt * 32) * D_DIM;
  const float* Yrow = Yp + (size_t)(bh * L_DIM + mt * 32) * D_DIM;
#pragma unroll
  for (int i = 0; i < 4; ++i) {  // 1024 float4 per tile, coalesced
    const int f = tid + 256 * i;
    const int l = f >> 5, dq = f & 31;
    *(float4*)&Xt[l][dq * 4] = *(const float4*)(Xrow + l * D_DIM + dq * 4);
    *(float4*)&Yt[l][dq * 4] = *(const float4*)(Yrow + l * D_DIM + dq * 4);
  }
  if (tid < 32) ((float4*)w3s)[tid] = ((const float4*)w3)[tid];
  __syncthreads();

  // C0 = sum(w3) + b3 via wave-64 butterfly
  const int lane = tid & 63;
  float wsum = w3s[lane] + w3s[lane + 64];
#pragma unroll
  for (int off = 32; off > 0; off >>= 1) wsum += __shfl_xor(wsum, off);
  const float C0 = wsum + b3[0];

  float a00 = 0.f, a01 = 0.f, a10 = 0.f, a11 = 0.f;
#pragma unroll 2
  for (int d = 0; d < 128; d += 4) {
    const float4 xa = *(const float4*)&Xt[ty][d];        // 16-way bcast, free
    const float4 xb = *(const float4*)&Xt[ty + 16][d];
    const float4 ya = *(const float4*)&Yt[tx][d];        // 2-way, free
    const float4 yb = *(const float4*)&Yt[tx + 16][d];
    const float4 wv = *(const float4*)&w3s[d];           // all-lane bcast
    ACC4(wv.x, xa.x, xb.x, ya.x, yb.x)
    ACC4(wv.y, xa.y, xb.y, ya.y, yb.y)
    ACC4(wv.z, xa.z, xb.z, ya.z, yb.z)
    ACC4(wv.w, xa.w, xb.w, ya.w, yb.w)
  }

  float* orow = out + ((size_t)(bh * L_DIM + lt * 32)) * L_DIM + mt * 32;
  orow[ty * L_DIM + tx]             = C0 - 2.f * a00;
  orow[ty * L_DIM + tx + 16]        = C0 - 2.f * a01;
  orow[(ty + 16) * L_DIM + tx]      = C0 - 2.f * a10;
  orow[(ty + 16) * L_DIM + tx + 16] = C0 - 2.f * a11;
}

extern "C" void kernel_launch(void* const* d_in, const int* in_sizes, int n_in,
                              void* d_out, int out_size, void* d_ws, size_t ws_size,
                              hipStream_t stream) {
  const float* X  = (const float*)d_in[0];
  const float* Y  = (const float*)d_in[1];
  const float* W1 = (const float*)d_in[2];
  const float* b1 = (const float*)d_in[3];
  const float* W2 = (const float*)d_in[4];
  const float* b2 = (const float*)d_in[5];
  const float* w3 = (const float*)d_in[6];
  const float* b3 = (const float*)d_in[7];
  float* out = (float*)d_out;

  float* Xsc = (float*)d_ws;                               // 2 MB, scaled X-proj
  float* Ypp = Xsc + (size_t)NBH * L_DIM * D_DIM;          // 2 MB, Y-proj

  hipLaunchKernelGGL(proj_kernel, dim3(256), dim3(256), 0, stream,
                     X, Y, W1, b1, W2, b2, Xsc, Ypp);
  hipLaunchKernelGGL(tanh_outer_kernel, dim3(512), dim3(256), 0, stream,
                     Xsc, Ypp, w3, b3, out);
}